// Round 10
// baseline (106.274 us; speedup 1.0000x reference)
//
#include <hip/hip_runtime.h>

// Elman RNN, T=2e6, I=2, H=30, O=1 — fully-folded MFMA chunked scan.
// Two independent 16-chunk chains per wave (A,B) sharing A-fragments/C;
// per chain-step one padded 32x32 matvec via 4x mfma_f32_16x16x16_f16:
//   A = [SC*W_hh | SC*W_ih ; W_fc 0 ; 0], B rows 0-29 = h_{t-1} (f16),
//   rows 30,31 = x_t; C = [SC*(b_ih+b_hh); b_fc; 0]
// => D rows 0-29 = SC*pre_t, row 30 = out[t-1] (g3 lanes' d_b[2]).
// SC = 2*log2(e): tanh(p) = 1 - 2*rcp(1 + exp2(SC*p)).
// x staged per 8-step window into double-buffered LDS (f16, coalesced).
//
// ROUND 10: ROLLED LOOPS. Rounds 4-9 fully unrolled ~56-160 steps ->
// 60-100 KB bodies >> 32 KB L1I; instruction fetch from L2 was the
// serialized binder (explains: +2nd wave only +10% [r6], data staging
// neutral [r7], +2nd chain neutral [r9], all pipes <31% busy). Windows
// and steps are now genuine loops (unroll disabled); body ~2-3 KB.

#define T_LEN     2000000
#define HID       30
#define CHUNK_LEN 32
#define BURN      23           // burn iters = 24 (windows 0-2)
#define NBLOCK    512          // 512 blk x 128 chunks = 65536 >= 62500
#define WSTEPS    8
#define NWIN      7            // 3 burn + 4 main

typedef __attribute__((ext_vector_type(4))) _Float16 half4;
typedef __attribute__((ext_vector_type(2))) __fp16   fp16x2;  // pkrtz type
typedef __attribute__((ext_vector_type(4))) float    float4v;

union h4u { half4 v4; fp16x2 v2[2]; unsigned u2[2]; };
union h2u { fp16x2 v; unsigned u; };

// ---- staging: window o covers steps o*8 .. o*8+7 of every chunk ----
// thread t serves chunk st_c = t>>1, slots {st_j, st_j+1, st_j+4, st_j+5},
// st_j = (t&1)*2;  x index = chunk*CHUNK_LEN - BURN + o*8 + slot (clamped).
#define STAGE_LOAD(o) {                                                      \
    const int tb = st_base_t + (o) * WSTEPS;                                 \
    int i0 = tb + st_j,     i1 = tb + st_j + 1;                              \
    int i2 = tb + st_j + 4, i3 = tb + st_j + 5;                              \
    i0 = i0 < 0 ? 0 : (i0 >= T_LEN ? T_LEN - 1 : i0);                        \
    i1 = i1 < 0 ? 0 : (i1 >= T_LEN ? T_LEN - 1 : i1);                        \
    i2 = i2 < 0 ? 0 : (i2 >= T_LEN ? T_LEN - 1 : i2);                        \
    i3 = i3 < 0 ? 0 : (i3 >= T_LEN ? T_LEN - 1 : i3);                        \
    stv0 = ((const float2*)x)[i0]; stv1 = ((const float2*)x)[i1];            \
    stv2 = ((const float2*)x)[i2]; stv3 = ((const float2*)x)[i3];            \
}
#define STAGE_WRITE(o) {                                                     \
    const int wb = ((o) & 1) * 1024;                                         \
    h2u c0, c1, c2, c3;                                                      \
    c0.v = __builtin_amdgcn_cvt_pkrtz(stv0.x, stv0.y);                       \
    c1.v = __builtin_amdgcn_cvt_pkrtz(stv1.x, stv1.y);                       \
    c2.v = __builtin_amdgcn_cvt_pkrtz(stv2.x, stv2.y);                       \
    c3.v = __builtin_amdgcn_cvt_pkrtz(stv3.x, stv3.y);                       \
    lds_x[wb + (st_j + 0) * 128 + st_c] = c0.u;                              \
    lds_x[wb + (st_j + 1) * 128 + st_c] = c1.u;                              \
    lds_x[wb + (st_j + 4) * 128 + st_c] = c2.u;                              \
    lds_x[wb + (st_j + 5) * 128 + st_c] = c3.u;                              \
}

// one step of BOTH chains; x read from LDS at top (ds_read latency is
// covered by the tanh+pack chain that precedes its use in b1)
#define STEP_BODY(s, MASKQ, STOREQ)                                          \
{                                                                            \
    const unsigned xcA = lds_x[rbA + (s) * 128];                             \
    const unsigned xcB = lds_x[rbB + (s) * 128];                             \
    float tA[8], tB[8];                                                      \
    _Pragma("unroll")                                                        \
    for (int i = 0; i < 4; ++i) {                                            \
        tA[i]   = 1.f - 2.f * __builtin_amdgcn_rcpf(1.f + __builtin_amdgcn_exp2f(d_tA[i])); \
        tA[4+i] = 1.f - 2.f * __builtin_amdgcn_rcpf(1.f + __builtin_amdgcn_exp2f(d_bA[i])); \
        tB[i]   = 1.f - 2.f * __builtin_amdgcn_rcpf(1.f + __builtin_amdgcn_exp2f(d_tB[i])); \
        tB[4+i] = 1.f - 2.f * __builtin_amdgcn_rcpf(1.f + __builtin_amdgcn_exp2f(d_bB[i])); \
    }                                                                        \
    if (MASKQ) {                                                             \
        /* only chain A of chunk 0 can have t < 1 (chain B starts at +512) */\
        const float m = (t_cur >= 1) ? 1.f : 0.f;                            \
        _Pragma("unroll")                                                    \
        for (int i = 0; i < 8; ++i) tA[i] *= m;                              \
    }                                                                        \
    h4u b0A, b1A, b0B, b1B;                                                  \
    b0A.v2[0] = __builtin_amdgcn_cvt_pkrtz(tA[0], tA[1]);                    \
    b0A.v2[1] = __builtin_amdgcn_cvt_pkrtz(tA[2], tA[3]);                    \
    b1A.v2[0] = __builtin_amdgcn_cvt_pkrtz(tA[4], tA[5]);                    \
    b1A.v2[1] = __builtin_amdgcn_cvt_pkrtz(tA[6], tA[7]);                    \
    b0B.v2[0] = __builtin_amdgcn_cvt_pkrtz(tB[0], tB[1]);                    \
    b0B.v2[1] = __builtin_amdgcn_cvt_pkrtz(tB[2], tB[3]);                    \
    b1B.v2[0] = __builtin_amdgcn_cvt_pkrtz(tB[4], tB[5]);                    \
    b1B.v2[1] = __builtin_amdgcn_cvt_pkrtz(tB[6], tB[7]);                    \
    if (g3) { b1A.u2[1] = xcA; b1B.u2[1] = xcB; }                            \
    d_tA = __builtin_amdgcn_mfma_f32_16x16x16f16(a_t0, b0A.v4, cT, 0, 0, 0); \
    d_bA = __builtin_amdgcn_mfma_f32_16x16x16f16(a_b0, b0A.v4, cB, 0, 0, 0); \
    d_tB = __builtin_amdgcn_mfma_f32_16x16x16f16(a_t0, b0B.v4, cT, 0, 0, 0); \
    d_bB = __builtin_amdgcn_mfma_f32_16x16x16f16(a_b0, b0B.v4, cB, 0, 0, 0); \
    d_tA = __builtin_amdgcn_mfma_f32_16x16x16f16(a_t1, b1A.v4, d_tA, 0, 0, 0); \
    d_bA = __builtin_amdgcn_mfma_f32_16x16x16f16(a_b1, b1A.v4, d_bA, 0, 0, 0); \
    d_tB = __builtin_amdgcn_mfma_f32_16x16x16f16(a_t1, b1B.v4, d_tB, 0, 0, 0); \
    d_bB = __builtin_amdgcn_mfma_f32_16x16x16f16(a_b1, b1B.v4, d_bB, 0, 0, 0); \
    if (STOREQ) {                                                            \
        const int ta = t_cur - 1;                                            \
        if (g3 && ta < my_endA) out[ta] = d_bA[2];                           \
        const int tb2 = ta + 16 * CHUNK_LEN;                                 \
        if (g3 && tb2 < my_endB) out[tb2] = d_bB[2];                         \
    }                                                                        \
    ++t_cur;                                                                 \
}

__global__ __launch_bounds__(256, 2)
void rnn_mfma_kernel(const float* __restrict__ x,
                     const float* __restrict__ W_ih,
                     const float* __restrict__ W_hh,
                     const float* __restrict__ b_ih,
                     const float* __restrict__ b_hh,
                     const float* __restrict__ W_fc,
                     const float* __restrict__ b_fc,
                     float* __restrict__ out)
{
    __shared__ unsigned lds_x[2 * WSTEPS * 128];  // [buf][slot][chunk] half2

    const int tid  = threadIdx.x;
    const int wave = tid >> 6;          // 0..3
    const int lane = tid & 63;
    const int g    = lane >> 4;         // reg-group 0..3
    const int cl   = lane & 15;         // A-row (top) / chunk column
    const bool g3  = (g == 3);

    // chain chunk ids: A = wave*32 + cl, B = A + 16 (within block's 128)
    const int rdA = wave * 32 + cl;
    const int rdB = rdA + 16;
    const int chunkA = blockIdx.x * 128 + rdA;
    const int chunkB = chunkA + 16;

    // staging role
    const int st_c = tid >> 1;                      // chunk-in-block 0..127
    const int st_j = (tid & 1) * 2;                 // slots j,j+1,j+4,j+5
    const int st_base_t = (blockIdx.x * 128 + st_c) * CHUNK_LEN - BURN;

    const float SC = 2.0f * 1.44269504088896340736f;   // 2*log2(e)

    // ---- static A fragments (f16), shared by both chains ----
    half4 a_t0, a_t1, a_b0, a_b1;
#pragma unroll
    for (int i = 0; i < 4; ++i) {
        const int k0 = 4*g + i;        // 0..15
        const int k1 = 16 + 4*g + i;   // 16..31
        const int mt = cl;             // rows 0..15
        const int mb = 16 + cl;        // rows 16..31

        a_t0[i] = (_Float16)(SC * W_hh[mt*HID + k0]);
        float v_t1;
        if (k1 < HID)        v_t1 = SC * W_hh[mt*HID + k1];
        else if (k1 == HID)  v_t1 = SC * W_ih[mt*2 + 0];
        else                 v_t1 = SC * W_ih[mt*2 + 1];
        a_t1[i] = (_Float16)v_t1;

        float v_b0, v_b1;
        if (mb < HID) {
            v_b0 = SC * W_hh[mb*HID + k0];
            if (k1 < HID)        v_b1 = SC * W_hh[mb*HID + k1];
            else if (k1 == HID)  v_b1 = SC * W_ih[mb*2 + 0];
            else                 v_b1 = SC * W_ih[mb*2 + 1];
        } else if (mb == HID) {        // FC row: unscaled, x-cols zero
            v_b0 = W_fc[k0];
            v_b1 = (k1 < HID) ? W_fc[k1] : 0.f;
        } else {                       // row 31: zero
            v_b0 = 0.f; v_b1 = 0.f;
        }
        a_b0[i] = (_Float16)v_b0;
        a_b1[i] = (_Float16)v_b1;
    }

    // ---- C operands: scaled biases; row30 = b_fc; row31 = 0 ----
    float4v cT, cB;
#pragma unroll
    for (int i = 0; i < 4; ++i) {
        const int rt  = 4*g + i;
        const int rb2 = 16 + 4*g + i;
        cT[i] = SC * (b_ih[rt] + b_hh[rt]);
        cB[i] = (rb2 < HID)  ? SC * (b_ih[rb2] + b_hh[rb2])
              : (rb2 == HID) ? b_fc[0] : 0.f;
    }

    int my_endA = chunkA * CHUNK_LEN + CHUNK_LEN;
    if (my_endA > T_LEN) my_endA = T_LEN;
    int my_endB = chunkB * CHUNK_LEN + CHUNK_LEN;
    if (my_endB > T_LEN) my_endB = T_LEN;

    __builtin_amdgcn_sched_barrier(0);

    float4v d_tA = {0.f,0.f,0.f,0.f}, d_bA = {0.f,0.f,0.f,0.f};
    float4v d_tB = {0.f,0.f,0.f,0.f}, d_bB = {0.f,0.f,0.f,0.f};

    int t_cur = chunkA * CHUNK_LEN - BURN;   // chain A time; B = A + 512

    float2 stv0, stv1, stv2, stv3;
    STAGE_LOAD(0)
    STAGE_WRITE(0)
    __syncthreads();

    // ---- burn windows 0-2 (24 steps, h masked while t_cur < 1) ----
#pragma clang loop unroll(disable)
    for (int o = 0; o < 3; ++o) {
        const int wb  = (o & 1) * 1024;
        const int rbA = wb + rdA, rbB = wb + rdB;
        STAGE_LOAD(o + 1)
#pragma clang loop unroll(disable)
        for (int s = 0; s < WSTEPS; ++s) {
            STEP_BODY(s, true, false)
        }
        STAGE_WRITE(o + 1)
        __syncthreads();
    }

    // ---- main windows 3-6 (32 steps, store out[t_cur-1]) ----
#pragma clang loop unroll(disable)
    for (int o = 3; o < NWIN; ++o) {
        const int wb  = (o & 1) * 1024;
        const int rbA = wb + rdA, rbB = wb + rdB;
        if (o < NWIN - 1) STAGE_LOAD(o + 1)
#pragma clang loop unroll(disable)
        for (int s = 0; s < WSTEPS; ++s) {
            STEP_BODY(s, false, true)
        }
        if (o < NWIN - 1) STAGE_WRITE(o + 1)
        __syncthreads();
    }
}

extern "C" void kernel_launch(void* const* d_in, const int* in_sizes, int n_in,
                              void* d_out, int out_size, void* d_ws, size_t ws_size,
                              hipStream_t stream)
{
    const float* x    = (const float*)d_in[0];
    const float* W_ih = (const float*)d_in[1];
    const float* W_hh = (const float*)d_in[2];
    const float* b_ih = (const float*)d_in[3];
    const float* b_hh = (const float*)d_in[4];
    const float* W_fc = (const float*)d_in[5];
    const float* b_fc = (const float*)d_in[6];
    float* out = (float*)d_out;

    // 512 blocks x 4 waves x 2 chains x 16 = 65536 chunks (>= 62500);
    // 2 blocks/CU = 2 waves/SIMD, 4 independent chains per SIMD
    rnn_mfma_kernel<<<NBLOCK, 256, 0, stream>>>(x, W_ih, W_hh, b_ih, b_hh,
                                                W_fc, b_fc, out);
}

// Round 11
// 99.599 us; speedup vs baseline: 1.0670x; 1.0670x over previous
//
#include <hip/hip_runtime.h>

// Elman RNN, T=2e6, I=2, H=30, O=1 — fully-folded MFMA chunked scan.
// ONE 16-chunk chain per wave, CHUNK_LEN 64, burn 16 (r11: burn overhead
// 50%->25%, total trans work -30% vs r10's 2-chain/len-32; r9/r10 showed
// extra chains buy nothing once loops are rolled — 2 waves/SIMD covers
// the chain latency). Loops stay ROLLED (r10: unrolled 60-100 KB bodies
// thrashed the 32 KB L1I; that was the r4-r9 binder).
// Per chain-step one padded 32x32 matvec via 4x mfma_f32_16x16x16_f16:
//   A = [SC*W_hh | SC*W_ih ; W_fc 0 ; 0], B rows 0-29 = h_{t-1} (f16),
//   rows 30,31 = x_t; C = [SC*(b_ih+b_hh); b_fc; 0]
// => D rows 0-29 = SC*pre_t, row 30 = out[t-1] (g3 lanes' d_b[2]).
// SC = 2*log2(e): tanh(p) = 1 - 2*rcp(1 + exp2(SC*p)).
// x staged per 8-step window into double-buffered LDS (f16, coalesced).

#define T_LEN     2000000
#define HID       30
#define CHUNK_LEN 64
#define BURN      15           // burn iters = 16 (windows 0-1)
#define NBLOCK    512          // 512 blk x 64 chunks = 32768 >= 31250
#define WSTEPS    8
#define NWIN      10           // 2 burn + 8 main

typedef __attribute__((ext_vector_type(4))) _Float16 half4;
typedef __attribute__((ext_vector_type(2))) __fp16   fp16x2;  // pkrtz type
typedef __attribute__((ext_vector_type(4))) float    float4v;

union h4u { half4 v4; fp16x2 v2[2]; unsigned u2[2]; };
union h2u { fp16x2 v; unsigned u; };

// ---- staging: window o covers steps o*8 .. o*8+7 of every chunk ----
// thread t serves chunk st_c = t>>2, slots {st_j, st_j+4}, st_j = t&3;
// x index = chunk*CHUNK_LEN - BURN + o*8 + slot (clamped).
#define STAGE_LOAD(o) {                                                      \
    const int tb = st_base_t + (o) * WSTEPS;                                 \
    int i0 = tb + st_j;                                                      \
    int i1 = tb + st_j + 4;                                                  \
    i0 = i0 < 0 ? 0 : (i0 >= T_LEN ? T_LEN - 1 : i0);                        \
    i1 = i1 < 0 ? 0 : (i1 >= T_LEN ? T_LEN - 1 : i1);                        \
    stv0 = ((const float2*)x)[i0];                                           \
    stv1 = ((const float2*)x)[i1];                                           \
}
#define STAGE_WRITE(o) {                                                     \
    const int wb = ((o) & 1) * 512;                                          \
    h2u c0, c1;                                                              \
    c0.v = __builtin_amdgcn_cvt_pkrtz(stv0.x, stv0.y);                       \
    c1.v = __builtin_amdgcn_cvt_pkrtz(stv1.x, stv1.y);                       \
    lds_x[wb + (st_j + 0) * 64 + st_c] = c0.u;                               \
    lds_x[wb + (st_j + 4) * 64 + st_c] = c1.u;                               \
}

// one chain-step; x read from LDS at top (latency covered by tanh chain)
#define STEP_BODY(s, MASKQ, STOREQ)                                          \
{                                                                            \
    const unsigned xc = lds_x[rbA + (s) * 64];                               \
    float th[8];                                                             \
    _Pragma("unroll")                                                        \
    for (int i = 0; i < 4; ++i) {                                            \
        th[i]   = 1.f - 2.f * __builtin_amdgcn_rcpf(1.f + __builtin_amdgcn_exp2f(d_t[i])); \
        th[4+i] = 1.f - 2.f * __builtin_amdgcn_rcpf(1.f + __builtin_amdgcn_exp2f(d_b[i])); \
    }                                                                        \
    if (MASKQ) {                                                             \
        const float m = (t_cur >= 1) ? 1.f : 0.f;                            \
        _Pragma("unroll")                                                    \
        for (int i = 0; i < 8; ++i) th[i] *= m;                              \
    }                                                                        \
    h4u b0, b1;                                                              \
    b0.v2[0] = __builtin_amdgcn_cvt_pkrtz(th[0], th[1]);                     \
    b0.v2[1] = __builtin_amdgcn_cvt_pkrtz(th[2], th[3]);                     \
    b1.v2[0] = __builtin_amdgcn_cvt_pkrtz(th[4], th[5]);                     \
    b1.v2[1] = __builtin_amdgcn_cvt_pkrtz(th[6], th[7]);                     \
    if (g3) b1.u2[1] = xc;                                                   \
    d_t = __builtin_amdgcn_mfma_f32_16x16x16f16(a_t0, b0.v4, cT, 0, 0, 0);   \
    d_b = __builtin_amdgcn_mfma_f32_16x16x16f16(a_b0, b0.v4, cB, 0, 0, 0);   \
    d_t = __builtin_amdgcn_mfma_f32_16x16x16f16(a_t1, b1.v4, d_t, 0, 0, 0);  \
    d_b = __builtin_amdgcn_mfma_f32_16x16x16f16(a_b1, b1.v4, d_b, 0, 0, 0);  \
    if (STOREQ) {                                                            \
        const int ta = t_cur - 1;                                            \
        if (g3 && ta < my_end) out[ta] = d_b[2];                             \
    }                                                                        \
    ++t_cur;                                                                 \
}

__global__ __launch_bounds__(256, 2)
void rnn_mfma_kernel(const float* __restrict__ x,
                     const float* __restrict__ W_ih,
                     const float* __restrict__ W_hh,
                     const float* __restrict__ b_ih,
                     const float* __restrict__ b_hh,
                     const float* __restrict__ W_fc,
                     const float* __restrict__ b_fc,
                     float* __restrict__ out)
{
    __shared__ unsigned lds_x[2 * WSTEPS * 64];   // [buf][slot][chunk] half2

    const int tid  = threadIdx.x;
    const int wave = tid >> 6;          // 0..3
    const int lane = tid & 63;
    const int g    = lane >> 4;         // reg-group 0..3
    const int cl   = lane & 15;         // A-row (top) / chunk column
    const bool g3  = (g == 3);

    const int rdA   = wave * 16 + cl;                  // chunk-in-block 0..63
    const int chunk = blockIdx.x * 64 + rdA;           // global chunk

    // staging role
    const int st_c = tid >> 2;                         // chunk-in-block 0..63
    const int st_j = tid & 3;                          // slots j, j+4
    const int st_base_t = (blockIdx.x * 64 + st_c) * CHUNK_LEN - BURN;

    const float SC = 2.0f * 1.44269504088896340736f;   // 2*log2(e)

    // ---- static A fragments (f16), padded per the header comment ----
    half4 a_t0, a_t1, a_b0, a_b1;
#pragma unroll
    for (int i = 0; i < 4; ++i) {
        const int k0 = 4*g + i;        // 0..15
        const int k1 = 16 + 4*g + i;   // 16..31
        const int mt = cl;             // rows 0..15
        const int mb = 16 + cl;        // rows 16..31

        a_t0[i] = (_Float16)(SC * W_hh[mt*HID + k0]);
        float v_t1;
        if (k1 < HID)        v_t1 = SC * W_hh[mt*HID + k1];
        else if (k1 == HID)  v_t1 = SC * W_ih[mt*2 + 0];
        else                 v_t1 = SC * W_ih[mt*2 + 1];
        a_t1[i] = (_Float16)v_t1;

        float v_b0, v_b1;
        if (mb < HID) {
            v_b0 = SC * W_hh[mb*HID + k0];
            if (k1 < HID)        v_b1 = SC * W_hh[mb*HID + k1];
            else if (k1 == HID)  v_b1 = SC * W_ih[mb*2 + 0];
            else                 v_b1 = SC * W_ih[mb*2 + 1];
        } else if (mb == HID) {        // FC row: unscaled, x-cols zero
            v_b0 = W_fc[k0];
            v_b1 = (k1 < HID) ? W_fc[k1] : 0.f;
        } else {                       // row 31: zero
            v_b0 = 0.f; v_b1 = 0.f;
        }
        a_b0[i] = (_Float16)v_b0;
        a_b1[i] = (_Float16)v_b1;
    }

    // ---- C operands: scaled biases; row30 = b_fc; row31 = 0 ----
    float4v cT, cB;
#pragma unroll
    for (int i = 0; i < 4; ++i) {
        const int rt  = 4*g + i;
        const int rb2 = 16 + 4*g + i;
        cT[i] = SC * (b_ih[rt] + b_hh[rt]);
        cB[i] = (rb2 < HID)  ? SC * (b_ih[rb2] + b_hh[rb2])
              : (rb2 == HID) ? b_fc[0] : 0.f;
    }

    int my_end = chunk * CHUNK_LEN + CHUNK_LEN;
    if (my_end > T_LEN) my_end = T_LEN;

    __builtin_amdgcn_sched_barrier(0);

    float4v d_t = {0.f,0.f,0.f,0.f}, d_b = {0.f,0.f,0.f,0.f};

    int t_cur = chunk * CHUNK_LEN - BURN;   // time of x consumed this step

    float2 stv0, stv1;
    STAGE_LOAD(0)
    STAGE_WRITE(0)
    __syncthreads();

    // ---- burn windows 0-1 (16 steps, h masked while t_cur < 1) ----
#pragma clang loop unroll(disable)
    for (int o = 0; o < 2; ++o) {
        const int rbA = (o & 1) * 512 + rdA;
        STAGE_LOAD(o + 1)
#pragma clang loop unroll(disable)
        for (int s = 0; s < WSTEPS; ++s) {
            STEP_BODY(s, true, false)
        }
        STAGE_WRITE(o + 1)
        __syncthreads();
    }

    // ---- main windows 2-9 (64 steps, store out[t_cur-1]) ----
#pragma clang loop unroll(disable)
    for (int o = 2; o < NWIN; ++o) {
        const int rbA = (o & 1) * 512 + rdA;
        if (o < NWIN - 1) STAGE_LOAD(o + 1)
#pragma clang loop unroll(disable)
        for (int s = 0; s < WSTEPS; ++s) {
            STEP_BODY(s, false, true)
        }
        if (o < NWIN - 1) STAGE_WRITE(o + 1)
        __syncthreads();
    }
}

extern "C" void kernel_launch(void* const* d_in, const int* in_sizes, int n_in,
                              void* d_out, int out_size, void* d_ws, size_t ws_size,
                              hipStream_t stream)
{
    const float* x    = (const float*)d_in[0];
    const float* W_ih = (const float*)d_in[1];
    const float* W_hh = (const float*)d_in[2];
    const float* b_ih = (const float*)d_in[3];
    const float* b_hh = (const float*)d_in[4];
    const float* W_fc = (const float*)d_in[5];
    const float* b_fc = (const float*)d_in[6];
    float* out = (float*)d_out;

    // 512 blocks x 4 waves x 16 chunks = 32768 chunks (>= 31250);
    // 2 blocks/CU = 2 waves/SIMD
    rnn_mfma_kernel<<<NBLOCK, 256, 0, stream>>>(x, W_ih, W_hh, b_ih, b_hh,
                                                W_fc, b_fc, out);
}